// Round 2
// baseline (796.271 us; speedup 1.0000x reference)
//
#include <hip/hip_runtime.h>
#include <hip/hip_bf16.h>

// Problem constants
#define BB 256
#define TT 1024
#define II 128
#define HH 64

typedef float  f32x4_t __attribute__((ext_vector_type(4)));
typedef short  s16x8_t __attribute__((ext_vector_type(8)));

__device__ __forceinline__ unsigned short f2bf(float f){
  unsigned u = __float_as_uint(f);
  u += 0x7FFFu + ((u >> 16) & 1u);          // round-to-nearest-even
  return (unsigned short)(u >> 16);
}
__device__ __forceinline__ float bf2f(unsigned short s){
  return __uint_as_float(((unsigned)s) << 16);
}
__device__ __forceinline__ float tanh_fast(float x){
  // tanh(x) = 1 - 2/(1+e^{2x});  e^{2x} = exp2(x * 2/ln2)
  float e = __builtin_amdgcn_exp2f(x * 2.88539004f);
  return __builtin_fmaf(-2.0f, __builtin_amdgcn_rcpf(1.0f + e), 1.0f);
}

// ---------------------------------------------------------------------------
// K1: Z2 block-diagonalization.
//   wsf[0..2047]   : W2 (64x32 row-major). Rows 0..31 = Bp, rows 32..63 = Bm.
//     Bp[i][j] = 0.5*(Ap[i][j] + Ap[i][j+32] + Ap[i+32][j] + Ap[i+32][j+32])
//     Bm[i][j] = 0.5*(Am[i][j] - Am[i][j+32] - Am[i+32][j] + Am[i+32][j+32])
//   wsf[2048..2111]: combined bias = W_in_b + bias
// ---------------------------------------------------------------------------
__global__ void k_prep(const float* __restrict__ Ap, const float* __restrict__ Am,
                       const float* __restrict__ Winb, const float* __restrict__ bias,
                       float* __restrict__ wsf){
  for (int e = threadIdx.x; e < 2048; e += blockDim.x){
    int i = e >> 5, j = e & 31;
    float val;
    if (i < 32){
      val = 0.5f * (Ap[i*64 + j] + Ap[i*64 + j + 32] + Ap[(i+32)*64 + j] + Ap[(i+32)*64 + j + 32]);
    } else {
      int i2 = i - 32;
      val = 0.5f * (Am[i2*64 + j] - Am[i2*64 + j + 32] - Am[(i2+32)*64 + j] + Am[(i2+32)*64 + j + 32]);
    }
    wsf[e] = val;
  }
  if (threadIdx.x < 64) wsf[2048 + threadIdx.x] = Winb[threadIdx.x] + bias[threadIdx.x];
}

// ---------------------------------------------------------------------------
// K2: U[b*T+t][h] = x[row,:] . W_in[h,:] + bc[h], stored bf16.
//     LDS-staged: coalesced float4 global loads into padded tile (stride 132
//     floats -> 2-way-free bank pattern on b128 fragment reads), then MFMA.
//     Block = 256 thr (4 waves), 64 rows/block; wave w owns rows w*16..w*16+15.
// ---------------------------------------------------------------------------
__global__ __launch_bounds__(256) void k_inproj(const float* __restrict__ x,
                                                const float* __restrict__ Win,
                                                const float* __restrict__ wsf,
                                                unsigned short* __restrict__ U){
  __shared__ float xs[64 * 132];
  const int tid  = threadIdx.x;
  const int lane = tid & 63;
  const int wave = tid >> 6;
  const int l15  = lane & 15;   // A: m-row, B: n-col, C: n-col
  const int q    = lane >> 4;   // A/B: k-chunk, C: m-row-quad

  // B fragments: B[k][n] = Win[n][k]; lane holds k = ks*32 + q*8 + j, n = nt*16 + l15
  s16x8_t bfr[4][4]; // [ks][nt]
  #pragma unroll
  for (int nt = 0; nt < 4; ++nt){
    #pragma unroll
    for (int ks = 0; ks < 4; ++ks){
      const float* src = Win + (nt*16 + l15) * II + ks*32 + q*8;
      float4 f0 = *(const float4*)(src);
      float4 f1 = *(const float4*)(src + 4);
      s16x8_t v;
      v[0]=(short)f2bf(f0.x); v[1]=(short)f2bf(f0.y); v[2]=(short)f2bf(f0.z); v[3]=(short)f2bf(f0.w);
      v[4]=(short)f2bf(f1.x); v[5]=(short)f2bf(f1.y); v[6]=(short)f2bf(f1.z); v[7]=(short)f2bf(f1.w);
      bfr[ks][nt] = v;
    }
  }
  float bcv[4];
  #pragma unroll
  for (int nt = 0; nt < 4; ++nt) bcv[nt] = wsf[2048 + nt*16 + l15];

  // Stage 64 rows x 128 floats (128 KB) with coalesced float4 loads.
  const long rowbase = (long)blockIdx.x * 64;
  const float* xg = x + rowbase * II;
  #pragma unroll
  for (int it = 0; it < 8; ++it){
    int flat = it * 1024 + tid * 4;
    int r = flat >> 7, c = flat & 127;
    float4 v = *(const float4*)(xg + flat);
    *(float4*)(&xs[r*132 + c]) = v;
  }
  __syncthreads();

  // A fragments for this wave's 16 rows, from LDS.
  const int row = wave * 16 + l15;
  s16x8_t afr[4];
  #pragma unroll
  for (int ks = 0; ks < 4; ++ks){
    const float* sp = &xs[row*132 + ks*32 + q*8];
    float4 a0 = *(const float4*)(sp);
    float4 a1 = *(const float4*)(sp + 4);
    s16x8_t v;
    v[0]=(short)f2bf(a0.x); v[1]=(short)f2bf(a0.y); v[2]=(short)f2bf(a0.z); v[3]=(short)f2bf(a0.w);
    v[4]=(short)f2bf(a1.x); v[5]=(short)f2bf(a1.y); v[6]=(short)f2bf(a1.z); v[7]=(short)f2bf(a1.w);
    afr[ks] = v;
  }

  f32x4_t acc[4];
  #pragma unroll
  for (int nt = 0; nt < 4; ++nt){
    acc[nt][0]=bcv[nt]; acc[nt][1]=bcv[nt]; acc[nt][2]=bcv[nt]; acc[nt][3]=bcv[nt];
  }
  #pragma unroll
  for (int ks = 0; ks < 4; ++ks){
    #pragma unroll
    for (int nt = 0; nt < 4; ++nt){
      acc[nt] = __builtin_amdgcn_mfma_f32_16x16x32_bf16(afr[ks], bfr[ks][nt], acc[nt], 0, 0, 0);
    }
  }
  // C layout: col = lane&15 (n), row = q*4 + r (m)
  const long rb = rowbase + wave * 16;
  #pragma unroll
  for (int nt = 0; nt < 4; ++nt){
    #pragma unroll
    for (int r = 0; r < 4; ++r){
      U[(rb + q*4 + r) * HH + nt*16 + l15] = f2bf(acc[nt][r]);
    }
  }
}

// ---------------------------------------------------------------------------
// K3: recurrence in the Z2 eigenbasis. One wave per batch.
//   Lane i<32 holds Bp row i; lane 32+i holds Bm row i (32 VGPRs -> resident).
//   Per step: v = fold(h) gives s_i (lanes<32) / d_i (lanes>=32);
//   ds_swizzle BitMode imm=(j<<5) broadcasts half-lane j within each 32-half
//   (DS pipe, no VALU cost); 32 fmas in 4 chains; cross-half exchange via
//   ds_bpermute; combine + tanh.
// ---------------------------------------------------------------------------
#define SW4(J) { \
  acc0 = __builtin_fmaf(w[(J)+0], __uint_as_float(__builtin_amdgcn_ds_swizzle(vv, (((J)+0)<<5))), acc0); \
  acc1 = __builtin_fmaf(w[(J)+1], __uint_as_float(__builtin_amdgcn_ds_swizzle(vv, (((J)+1)<<5))), acc1); \
  acc2 = __builtin_fmaf(w[(J)+2], __uint_as_float(__builtin_amdgcn_ds_swizzle(vv, (((J)+2)<<5))), acc2); \
  acc3 = __builtin_fmaf(w[(J)+3], __uint_as_float(__builtin_amdgcn_ds_swizzle(vv, (((J)+3)<<5))), acc3); \
}

__global__ __launch_bounds__(64) void k_rnn(const float* __restrict__ wsf,
                                            const unsigned short* __restrict__ U,
                                            const float* __restrict__ Wout,
                                            const float* __restrict__ Woutb,
                                            float* __restrict__ out){
  const int b    = blockIdx.x;
  const int lane = threadIdx.x;

  float w[32];
  {
    const float4* wr = (const float4*)(wsf + lane * 32);
    #pragma unroll
    for (int j4 = 0; j4 < 8; ++j4){
      float4 v = wr[j4];
      w[4*j4+0] = v.x; w[4*j4+1] = v.y; w[4*j4+2] = v.z; w[4*j4+3] = v.w;
    }
  }
  const float sgn  = (lane < 32) ? 1.0f : -1.0f;  // combine sign
  const float sgnh = 0.5f * sgn;                  // fold sign*0.5
  const int   xidx = (lane ^ 32) << 2;            // bpermute byte index

  const unsigned short* Ub = U + (long)b * (TT * HH) + lane;
  float uc[4], un[4];
  #pragma unroll
  for (int g = 0; g < 4; ++g) uc[g] = bf2f(Ub[g * HH]);

  float h = 0.0f;
  for (int tg = 0; tg < TT/4; ++tg){
    const int tn = (tg + 1) * 4;
    #pragma unroll
    for (int g = 0; g < 4; ++g){
      int t = tn + g; if (t > TT-1) t = TT-1;
      un[g] = bf2f(Ub[t * HH]);
    }
    #pragma unroll
    for (int g = 0; g < 4; ++g){
      // fold: v = s_lane (lanes<32) / d_{lane-32} (lanes>=32)
      float t = __uint_as_float(__builtin_amdgcn_ds_bpermute(xidx, __float_as_uint(h)));
      float v = __builtin_fmaf(h, sgnh, t * 0.5f);
      unsigned vv = __float_as_uint(v);
      float acc0 = 0.0f, acc1 = 0.0f, acc2 = 0.0f, acc3 = 0.0f;
      SW4(0) SW4(4) SW4(8) SW4(12) SW4(16) SW4(20) SW4(24) SW4(28)
      float pq = (acc0 + acc1) + (acc2 + acc3);   // p_i (lanes<32) / q_i (>=32)
      float t2 = __uint_as_float(__builtin_amdgcn_ds_bpermute(xidx, __float_as_uint(pq)));
      float y  = __builtin_fmaf(pq, sgn, t2) + uc[g];  // p+q / p-q
      h = tanh_fast(y);
    }
    #pragma unroll
    for (int g = 0; g < 4; ++g) uc[g] = un[g];
  }

  // Epilogue: predictions[b] = W_out @ h + W_out_b ; hidden[b] = h
  unsigned hu = __float_as_uint(h);
  float p0 = Woutb[lane];
  float p1 = Woutb[lane + 64];
  #pragma unroll 8
  for (int j = 0; j < 64; ++j){
    float hj = __uint_as_float(__builtin_amdgcn_readlane(hu, j));
    p0 = __builtin_fmaf(Wout[lane * HH + j],        hj, p0);
    p1 = __builtin_fmaf(Wout[(lane + 64) * HH + j], hj, p1);
  }
  out[b * 128 + lane]           = p0;
  out[b * 128 + 64 + lane]      = p1;
  out[BB * 128 + b * 64 + lane] = h;
}

// ---------------------------------------------------------------------------
extern "C" void kernel_launch(void* const* d_in, const int* in_sizes, int n_in,
                              void* d_out, int out_size, void* d_ws, size_t ws_size,
                              hipStream_t stream){
  const float* x     = (const float*)d_in[0];
  const float* Ap    = (const float*)d_in[1];
  const float* Am    = (const float*)d_in[2];
  const float* Winw  = (const float*)d_in[3];
  const float* Winb  = (const float*)d_in[4];
  const float* Woutw = (const float*)d_in[5];
  const float* Woutb = (const float*)d_in[6];
  const float* bias  = (const float*)d_in[7];

  float*          wsf = (float*)d_ws;
  unsigned short* U   = (unsigned short*)((char*)d_ws + 32768);  // needs ~33.6 MB total
  float*          out = (float*)d_out;

  hipLaunchKernelGGL(k_prep,   dim3(1),    dim3(256), 0, stream, Ap, Am, Winb, bias, wsf);
  hipLaunchKernelGGL(k_inproj, dim3(4096), dim3(256), 0, stream, x, Winw, wsf, U);
  hipLaunchKernelGGL(k_rnn,    dim3(BB),   dim3(64),  0, stream, wsf, U, Woutw, Woutb, out);
}

// Round 3
// 463.440 us; speedup vs baseline: 1.7182x; 1.7182x over previous
//
#include <hip/hip_runtime.h>
#include <hip/hip_bf16.h>

// Problem constants
#define BB 256
#define TT 1024
#define II 128
#define HH 64

typedef float  f32x4_t __attribute__((ext_vector_type(4)));
typedef short  s16x8_t __attribute__((ext_vector_type(8)));

__device__ __forceinline__ unsigned short f2bf(float f){
  unsigned u = __float_as_uint(f);
  u += 0x7FFFu + ((u >> 16) & 1u);          // round-to-nearest-even
  return (unsigned short)(u >> 16);
}
__device__ __forceinline__ float bf2f(unsigned short s){
  return __uint_as_float(((unsigned)s) << 16);
}
__device__ __forceinline__ float tanh_fast(float x){
  // tanh(x) = 1 - 2/(1+e^{2x});  e^{2x} = exp2(x * 2/ln2)
  float e = __builtin_amdgcn_exp2f(x * 2.88539004f);
  return __builtin_fmaf(-2.0f, __builtin_amdgcn_rcpf(1.0f + e), 1.0f);
}

// ---------------------------------------------------------------------------
// Workspace layout (floats at wsf, shorts at wsb, U after 64 KB):
//   wsf[0..4095]   : W_comm 64x64 row-major
//   wsf[4096..4159]: combined bias = W_in_b + bias
//   wsb[0..8191]   : W_in bf16 MFMA B-fragments, frag-ready:
//                    wsb[((ks*4+nt)*64 + lane)*8 + j] = bf16(Win[(nt*16+l15)*128 + ks*32 + q*8 + j])
//   U (bf16) at byte offset 65536, layout [b][h][t]  (t contiguous)
// ---------------------------------------------------------------------------
__global__ void k_prep(const float* __restrict__ Ap, const float* __restrict__ Am,
                       const float* __restrict__ Winw,
                       const float* __restrict__ Winb, const float* __restrict__ bias,
                       float* __restrict__ wsf, unsigned short* __restrict__ wsb){
  const int tid = threadIdx.x;
  for (int e = tid; e < 4096; e += 256){
    int i = e >> 6, j = e & 63;
    int is = i ^ 32, js = j ^ 32;
    float wp = Ap[i*64+j] + Ap[i*64+js] + Ap[is*64+j] + Ap[is*64+js];
    float wm = Am[i*64+j] - Am[i*64+js] - Am[is*64+j] + Am[is*64+js];
    wsf[e] = 0.25f * (wp + wm);
  }
  if (tid < 64) wsf[4096 + tid] = Winb[tid] + bias[tid];
  for (int e = tid; e < 8192; e += 256){
    int j = e & 7, lane = (e >> 3) & 63, fidx = e >> 9;
    int ks = fidx >> 2, nt = fidx & 3, l15 = lane & 15, q = lane >> 4;
    wsb[e] = f2bf(Winw[(nt*16 + l15)*II + ks*32 + q*8 + j]);
  }
}

// ---------------------------------------------------------------------------
// K2: U[b][h][t] = x[b,t,:] . W_in[h,:] + bc[h]  (bf16, t-contiguous layout).
//     1024 blocks x 256 thr; wave handles 64 rows (4 m-tiles of 16).
//     B-fragments loaded pre-converted from wsb (16 x 16B coalesced loads).
//     A direct from global (float4 pairs -> cache-line efficient).
//     Store: acc[nt][0..3] are 4 consecutive t -> one packed 8-B store.
// ---------------------------------------------------------------------------
__global__ __launch_bounds__(256) void k_inproj(const float* __restrict__ x,
                                                const float* __restrict__ wsf,
                                                const unsigned short* __restrict__ wsb,
                                                unsigned short* __restrict__ U){
  const int tid  = threadIdx.x;
  const int lane = tid & 63;
  const int wave = tid >> 6;
  const int l15  = lane & 15;
  const int q    = lane >> 4;

  s16x8_t bfr[4][4]; // [ks][nt]
  #pragma unroll
  for (int ks = 0; ks < 4; ++ks)
    #pragma unroll
    for (int nt = 0; nt < 4; ++nt)
      bfr[ks][nt] = *(const s16x8_t*)(wsb + ((ks*4 + nt)*64 + lane)*8);

  float bcv[4];
  #pragma unroll
  for (int nt = 0; nt < 4; ++nt) bcv[nt] = wsf[4096 + nt*16 + l15];

  const long rowbase = (long)blockIdx.x * 256 + (long)wave * 64;
  const int  b     = (int)(rowbase >> 10);
  const int  tbase = (int)(rowbase & 1023);
  unsigned short* Ub = U + (long)b * (HH * TT);

  #pragma unroll 1
  for (int mt = 0; mt < 4; ++mt){
    const long rb = rowbase + mt*16;
    const float* xa = x + (rb + l15) * II + q*8;
    s16x8_t afr[4];
    #pragma unroll
    for (int ks = 0; ks < 4; ++ks){
      float4 a0 = *(const float4*)(xa + ks*32);
      float4 a1 = *(const float4*)(xa + ks*32 + 4);
      s16x8_t v;
      v[0]=(short)f2bf(a0.x); v[1]=(short)f2bf(a0.y); v[2]=(short)f2bf(a0.z); v[3]=(short)f2bf(a0.w);
      v[4]=(short)f2bf(a1.x); v[5]=(short)f2bf(a1.y); v[6]=(short)f2bf(a1.z); v[7]=(short)f2bf(a1.w);
      afr[ks] = v;
    }
    f32x4_t acc[4];
    #pragma unroll
    for (int nt = 0; nt < 4; ++nt){
      acc[nt][0]=bcv[nt]; acc[nt][1]=bcv[nt]; acc[nt][2]=bcv[nt]; acc[nt][3]=bcv[nt];
    }
    #pragma unroll
    for (int ks = 0; ks < 4; ++ks){
      #pragma unroll
      for (int nt = 0; nt < 4; ++nt){
        acc[nt] = __builtin_amdgcn_mfma_f32_16x16x32_bf16(afr[ks], bfr[ks][nt], acc[nt], 0, 0, 0);
      }
    }
    // C layout: col(h) = nt*16 + l15, rows(t) = q*4 + r  -> 4 consecutive t
    const int t0 = tbase + mt*16 + q*4;
    #pragma unroll
    for (int nt = 0; nt < 4; ++nt){
      unsigned lo = (unsigned)f2bf(acc[nt][0]) | ((unsigned)f2bf(acc[nt][1]) << 16);
      unsigned hi = (unsigned)f2bf(acc[nt][2]) | ((unsigned)f2bf(acc[nt][3]) << 16);
      uint2 pk; pk.x = lo; pk.y = hi;
      *(uint2*)(Ub + (nt*16 + l15)*TT + t0) = pk;
    }
  }
}

// ---------------------------------------------------------------------------
// K3: recurrence. One wave per batch; lane i owns W_comm row i in 64 VGPRs
//     (launch_bounds(64,1) -> 512-VGPR budget, keeps w[] out of AGPRs).
//     Broadcast h[j] via v_readlane (VALU pipe). U is [b][h][t]: lane reads
//     its own contiguous bf16 stream, ushort4 per 4-step group, prefetch
//     2 groups (8 steps) ahead.
// ---------------------------------------------------------------------------
__global__ __launch_bounds__(64, 1) void k_rnn(const float* __restrict__ wsf,
                                               const unsigned short* __restrict__ U,
                                               const float* __restrict__ Wout,
                                               const float* __restrict__ Woutb,
                                               float* __restrict__ out){
  const int b    = blockIdx.x;
  const int lane = threadIdx.x;

  float w[64];
  {
    const float4* wr = (const float4*)(wsf + lane * 64);
    #pragma unroll
    for (int j4 = 0; j4 < 16; ++j4){
      float4 v = wr[j4];
      w[4*j4+0] = v.x; w[4*j4+1] = v.y; w[4*j4+2] = v.z; w[4*j4+3] = v.w;
    }
  }

  const ushort4* Ub = (const ushort4*)(U + (long)b * (HH * TT) + lane * TT);
  ushort4 uc = Ub[0];
  ushort4 u1 = Ub[1];

  float h = 0.0f;
  for (int tg = 0; tg < TT/4; ++tg){
    int tp = tg + 2; if (tp > TT/4 - 1) tp = TT/4 - 1;
    ushort4 u2 = Ub[tp];
    float ug0 = bf2f(uc.x), ug1 = bf2f(uc.y), ug2 = bf2f(uc.z), ug3 = bf2f(uc.w);
    #pragma unroll
    for (int g = 0; g < 4; ++g){
      float ugv = (g==0) ? ug0 : (g==1) ? ug1 : (g==2) ? ug2 : ug3;
      float a0 = ugv, a1 = 0.0f, a2 = 0.0f, a3 = 0.0f;
      unsigned hu = __float_as_uint(h);
      #pragma unroll
      for (int j = 0; j < 64; j += 4){
        a0 = __builtin_fmaf(w[j+0], __uint_as_float(__builtin_amdgcn_readlane(hu, j+0)), a0);
        a1 = __builtin_fmaf(w[j+1], __uint_as_float(__builtin_amdgcn_readlane(hu, j+1)), a1);
        a2 = __builtin_fmaf(w[j+2], __uint_as_float(__builtin_amdgcn_readlane(hu, j+2)), a2);
        a3 = __builtin_fmaf(w[j+3], __uint_as_float(__builtin_amdgcn_readlane(hu, j+3)), a3);
      }
      h = tanh_fast((a0 + a1) + (a2 + a3));
    }
    uc = u1; u1 = u2;
  }

  // Epilogue: predictions[b] = W_out @ h + W_out_b ; hidden[b] = h
  unsigned hu = __float_as_uint(h);
  float p0 = Woutb[lane];
  float p1 = Woutb[lane + 64];
  #pragma unroll 8
  for (int j = 0; j < 64; ++j){
    float hj = __uint_as_float(__builtin_amdgcn_readlane(hu, j));
    p0 = __builtin_fmaf(Wout[lane * HH + j],        hj, p0);
    p1 = __builtin_fmaf(Wout[(lane + 64) * HH + j], hj, p1);
  }
  out[b * 128 + lane]           = p0;
  out[b * 128 + 64 + lane]      = p1;
  out[BB * 128 + b * 64 + lane] = h;
}

// ---------------------------------------------------------------------------
extern "C" void kernel_launch(void* const* d_in, const int* in_sizes, int n_in,
                              void* d_out, int out_size, void* d_ws, size_t ws_size,
                              hipStream_t stream){
  const float* x     = (const float*)d_in[0];
  const float* Ap    = (const float*)d_in[1];
  const float* Am    = (const float*)d_in[2];
  const float* Winw  = (const float*)d_in[3];
  const float* Winb  = (const float*)d_in[4];
  const float* Woutw = (const float*)d_in[5];
  const float* Woutb = (const float*)d_in[6];
  const float* bias  = (const float*)d_in[7];

  float*          wsf = (float*)d_ws;
  unsigned short* wsb = (unsigned short*)((char*)d_ws + 4160 * 4);
  unsigned short* U   = (unsigned short*)((char*)d_ws + 65536);  // ~33.6 MB total

  float* out = (float*)d_out;

  hipLaunchKernelGGL(k_prep,   dim3(1),    dim3(256), 0, stream, Ap, Am, Winw, Winb, bias, wsf, wsb);
  hipLaunchKernelGGL(k_inproj, dim3(1024), dim3(256), 0, stream, x, wsf, wsb, U);
  hipLaunchKernelGGL(k_rnn,    dim3(BB),   dim3(64),  0, stream, wsf, U, Woutw, Woutb, out);
}

// Round 5
// 393.411 us; speedup vs baseline: 2.0240x; 1.1780x over previous
//
#include <hip/hip_runtime.h>
#include <hip/hip_bf16.h>

// Problem constants
#define BB 256
#define TT 1024
#define II 128
#define HH 64

typedef float    f32x4_t __attribute__((ext_vector_type(4)));
typedef _Float16 h16x2   __attribute__((ext_vector_type(2)));
typedef _Float16 h16x4   __attribute__((ext_vector_type(4)));
typedef _Float16 h16x8   __attribute__((ext_vector_type(8)));
typedef __fp16   p16x2   __attribute__((ext_vector_type(2)));

union UH2 { unsigned u; h16x2 h; p16x2 p; };
union U4H8 { uint4 u; h16x8 h; };

__device__ __forceinline__ float tanh_fast(float x){
  // tanh(x) = 1 - 2/(1+e^{2x});  e^{2x} = exp2(x * 2/ln2)
  float e = __builtin_amdgcn_exp2f(x * 2.88539004f);
  return __builtin_fmaf(-2.0f, __builtin_amdgcn_rcpf(1.0f + e), 1.0f);
}

#if __has_builtin(__builtin_amdgcn_fdot2)
__device__ __forceinline__ float fdot2f(h16x2 a, h16x2 b, float c){
  return __builtin_amdgcn_fdot2(a, b, c, false);
}
#else
__device__ __forceinline__ float fdot2f(h16x2 a, h16x2 b, float c){
  return __builtin_fmaf((float)a[1], (float)b[1], __builtin_fmaf((float)a[0], (float)b[0], c));
}
#endif

// ---------------------------------------------------------------------------
// Workspace layout:
//   wsf (f32)  @ 0      [4160]: W_comm 64x64 row-major + combined bias[64]
//   whf (u32)  @ 16640  [2048]: W_comm rows as packed f16x2 pairs:
//                               whf[i*32+jp] = {f16(W[i][2jp]), f16(W[i][2jp+1])}
//   wsb (u16)  @ 24832  [8192]: W_in f16 MFMA B-fragments, frag-ready
//   U   (f16)  @ 65536  [256*64*1024]: layout [b][h][t] (t contiguous)
// ---------------------------------------------------------------------------
__global__ void k_prep(const float* __restrict__ Ap, const float* __restrict__ Am,
                       const float* __restrict__ Winw,
                       const float* __restrict__ Winb, const float* __restrict__ bias,
                       float* __restrict__ wsf, unsigned* __restrict__ whf,
                       unsigned short* __restrict__ wsb){
  const int tid = threadIdx.x;
  for (int e = tid; e < 4096; e += 256){
    int i = e >> 6, j = e & 63;
    int is = i ^ 32, js = j ^ 32;
    float wp = Ap[i*64+j] + Ap[i*64+js] + Ap[is*64+j] + Ap[is*64+js];
    float wm = Am[i*64+j] - Am[i*64+js] - Am[is*64+j] + Am[is*64+js];
    wsf[e] = 0.25f * (wp + wm);
  }
  if (tid < 64) wsf[4096 + tid] = Winb[tid] + bias[tid];
  for (int e = tid; e < 8192; e += 256){
    int j = e & 7, lane = (e >> 3) & 63, fidx = e >> 9;
    int ks = fidx >> 2, nt = fidx & 3, l15 = lane & 15, q = lane >> 4;
    union { _Float16 f; unsigned short s; } cv;
    cv.f = (_Float16)Winw[(nt*16 + l15)*II + ks*32 + q*8 + j];
    wsb[e] = cv.s;
  }
  __syncthreads();
  for (int e = tid; e < 2048; e += 256){
    int i = e >> 5, jp = e & 31;
    UH2 p;
    p.h[0] = (_Float16)wsf[i*64 + 2*jp];
    p.h[1] = (_Float16)wsf[i*64 + 2*jp + 1];
    whf[e] = p.u;
  }
}

// ---------------------------------------------------------------------------
// K2: U[b][h][t] = f16( x[b,t,:] . W_in[h,:] + bc[h] ).
//     f16 MFMA 16x16x32. Block = 256 thr (4 waves); wave owns 64 t-rows.
//     Epilogue: acc -> per-wave LDS tile -> transposed full-line dwordx4
//     stores (no partial-line write amplification).
// ---------------------------------------------------------------------------
__global__ __launch_bounds__(256) void k_inproj(const float* __restrict__ x,
                                                const float* __restrict__ wsf,
                                                const unsigned short* __restrict__ wsb,
                                                unsigned short* __restrict__ U){
  __shared__ unsigned short xs[4 * 64 * 80];   // 4 waves x (64 h-rows x 80 f16, 160B stride)
  const int tid  = threadIdx.x;
  const int lane = tid & 63;
  const int wave = tid >> 6;
  const int l15  = lane & 15;
  const int q    = lane >> 4;

  h16x8 bfr[4][4]; // [ks][nt]
  #pragma unroll
  for (int ks = 0; ks < 4; ++ks)
    #pragma unroll
    for (int nt = 0; nt < 4; ++nt)
      bfr[ks][nt] = *(const h16x8*)(wsb + ((ks*4 + nt)*64 + lane)*8);

  float bcv[4];
  #pragma unroll
  for (int nt = 0; nt < 4; ++nt) bcv[nt] = wsf[4096 + nt*16 + l15];

  const long rowbase = (long)blockIdx.x * 256 + (long)wave * 64;
  const int  b     = (int)(rowbase >> 10);
  const int  tbase = (int)(rowbase & 1023);
  unsigned short* Ub = U + (long)b * (HH * TT);
  const int sbase = wave * 64 * 80;

  #pragma unroll 1
  for (int mt = 0; mt < 4; ++mt){
    const float* xa = x + (rowbase + mt*16 + l15) * II + q*8;
    h16x8 afr[4];
    #pragma unroll
    for (int ks = 0; ks < 4; ++ks){
      float4 a0 = *(const float4*)(xa + ks*32);
      float4 a1 = *(const float4*)(xa + ks*32 + 4);
      U4H8 v;
      UH2 p0, p1, p2, p3;
      p0.p = __builtin_amdgcn_cvt_pkrtz(a0.x, a0.y);
      p1.p = __builtin_amdgcn_cvt_pkrtz(a0.z, a0.w);
      p2.p = __builtin_amdgcn_cvt_pkrtz(a1.x, a1.y);
      p3.p = __builtin_amdgcn_cvt_pkrtz(a1.z, a1.w);
      v.u.x = p0.u; v.u.y = p1.u; v.u.z = p2.u; v.u.w = p3.u;
      afr[ks] = v.h;
    }
    f32x4_t acc[4];
    #pragma unroll
    for (int nt = 0; nt < 4; ++nt){
      acc[nt][0]=bcv[nt]; acc[nt][1]=bcv[nt]; acc[nt][2]=bcv[nt]; acc[nt][3]=bcv[nt];
    }
    #pragma unroll
    for (int ks = 0; ks < 4; ++ks){
      #pragma unroll
      for (int nt = 0; nt < 4; ++nt){
        acc[nt] = __builtin_amdgcn_mfma_f32_16x16x32_f16(afr[ks], bfr[ks][nt], acc[nt], 0, 0, 0);
      }
    }
    // C layout: h = nt*16 + l15, t(in tile) = mt*16 + q*4 + r  -> 4 consecutive t
    #pragma unroll
    for (int nt = 0; nt < 4; ++nt){
      UH2 lo, hi;
      lo.p = __builtin_amdgcn_cvt_pkrtz(acc[nt][0], acc[nt][1]);
      hi.p = __builtin_amdgcn_cvt_pkrtz(acc[nt][2], acc[nt][3]);
      uint2 pk; pk.x = lo.u; pk.y = hi.u;
      *(uint2*)&xs[sbase + (nt*16 + l15)*80 + mt*16 + q*4] = pk;
    }
  }
  __syncthreads();

  // Transposed store: 8 h-rows per instr, 8 lanes x 16B per h-row = full 128B lines.
  #pragma unroll
  for (int it = 0; it < 8; ++it){
    const int h    = it*8 + (lane >> 3);
    const int toff = (lane & 7) * 8;
    uint4 v = *(const uint4*)&xs[sbase + h*80 + toff];
    *(uint4*)(Ub + h*TT + tbase + toff) = v;
  }
}

// ---------------------------------------------------------------------------
// K3: recurrence. One wave per batch. Lane i owns W_comm row i as 32 packed
//     f16x2 VGPRs. Per step: DPP quad-perm (VALU) fetches neighbor h, one
//     cvt_pkrtz packs {h2j,h2j+1}; 32 readlane + 32 v_dot2_f32_f16 in 4
//     chains. u stream: per-lane contiguous f16, 8B per 4 steps, 2 groups
//     prefetch.
// ---------------------------------------------------------------------------
__global__ __launch_bounds__(64, 1) void k_rnn(const unsigned* __restrict__ whf,
                                               const unsigned short* __restrict__ Uu,
                                               const float* __restrict__ Wout,
                                               const float* __restrict__ Woutb,
                                               float* __restrict__ out){
  const int b    = blockIdx.x;
  const int lane = threadIdx.x;

  h16x2 w[32];
  {
    const uint4* wr = (const uint4*)(whf + lane * 32);
    #pragma unroll
    for (int j4 = 0; j4 < 8; ++j4){
      uint4 v = wr[j4];
      UH2 c0, c1, c2, c3;
      c0.u = v.x; c1.u = v.y; c2.u = v.z; c3.u = v.w;
      w[4*j4+0] = c0.h; w[4*j4+1] = c1.h; w[4*j4+2] = c2.h; w[4*j4+3] = c3.h;
    }
  }

  const h16x4* Ub = (const h16x4*)(Uu + (long)b * (HH * TT) + lane * TT);
  h16x4 uc = Ub[0];
  h16x4 u1 = Ub[1];

  float h = 0.0f;
  for (int tg = 0; tg < TT/4; ++tg){
    int tp = tg + 2; if (tp > TT/4 - 1) tp = TT/4 - 1;
    h16x4 u2 = Ub[tp];
    float ug0 = (float)uc[0], ug1 = (float)uc[1], ug2 = (float)uc[2], ug3 = (float)uc[3];
    #pragma unroll
    for (int g = 0; g < 4; ++g){
      float ugv = (g==0) ? ug0 : (g==1) ? ug1 : (g==2) ? ug2 : ug3;
      // neighbor h via DPP quad-perm [1,0,3,2] (VALU pipe)
      unsigned nbu = (unsigned)__builtin_amdgcn_mov_dpp(__float_as_uint(h), 0xB1, 0xF, 0xF, true);
      UH2 hp; hp.p = __builtin_amdgcn_cvt_pkrtz(h, __uint_as_float(nbu)); // valid on even lanes
      const unsigned hpu = hp.u;
      float a0 = ugv, a1 = 0.0f, a2 = 0.0f, a3 = 0.0f;
      #pragma unroll
      for (int jp = 0; jp < 32; jp += 4){
        UH2 b0, b1, b2, b3;
        b0.u = (unsigned)__builtin_amdgcn_readlane(hpu, 2*jp + 0);
        b1.u = (unsigned)__builtin_amdgcn_readlane(hpu, 2*jp + 2);
        b2.u = (unsigned)__builtin_amdgcn_readlane(hpu, 2*jp + 4);
        b3.u = (unsigned)__builtin_amdgcn_readlane(hpu, 2*jp + 6);
        a0 = fdot2f(w[jp+0], b0.h, a0);
        a1 = fdot2f(w[jp+1], b1.h, a1);
        a2 = fdot2f(w[jp+2], b2.h, a2);
        a3 = fdot2f(w[jp+3], b3.h, a3);
      }
      h = tanh_fast((a0 + a1) + (a2 + a3));
    }
    uc = u1; u1 = u2;
  }

  // Epilogue: predictions[b] = W_out @ h + W_out_b ; hidden[b] = h
  unsigned hu = __float_as_uint(h);
  float p0 = Woutb[lane];
  float p1 = Woutb[lane + 64];
  #pragma unroll 8
  for (int j = 0; j < 64; ++j){
    float hj = __uint_as_float(__builtin_amdgcn_readlane(hu, j));
    p0 = __builtin_fmaf(Wout[lane * HH + j],        hj, p0);
    p1 = __builtin_fmaf(Wout[(lane + 64) * HH + j], hj, p1);
  }
  out[b * 128 + lane]           = p0;
  out[b * 128 + 64 + lane]      = p1;
  out[BB * 128 + b * 64 + lane] = h;
}

// ---------------------------------------------------------------------------
extern "C" void kernel_launch(void* const* d_in, const int* in_sizes, int n_in,
                              void* d_out, int out_size, void* d_ws, size_t ws_size,
                              hipStream_t stream){
  const float* x     = (const float*)d_in[0];
  const float* Ap    = (const float*)d_in[1];
  const float* Am    = (const float*)d_in[2];
  const float* Winw  = (const float*)d_in[3];
  const float* Winb  = (const float*)d_in[4];
  const float* Woutw = (const float*)d_in[5];
  const float* Woutb = (const float*)d_in[6];
  const float* bias  = (const float*)d_in[7];

  float*          wsf = (float*)d_ws;
  unsigned*       whf = (unsigned*)((char*)d_ws + 16640);
  unsigned short* wsb = (unsigned short*)((char*)d_ws + 24832);
  unsigned short* U   = (unsigned short*)((char*)d_ws + 65536);  // ~33.6 MB total

  float* out = (float*)d_out;

  hipLaunchKernelGGL(k_prep,   dim3(1),    dim3(256), 0, stream, Ap, Am, Winw, Winb, bias, wsf, whf, wsb);
  hipLaunchKernelGGL(k_inproj, dim3(1024), dim3(256), 0, stream, x, wsf, wsb, U);
  hipLaunchKernelGGL(k_rnn,    dim3(BB),   dim3(64),  0, stream, whf, U, Woutw, Woutb, out);
}

// Round 6
// 382.139 us; speedup vs baseline: 2.0837x; 1.0295x over previous
//
#include <hip/hip_runtime.h>
#include <hip/hip_bf16.h>

// Problem constants
#define BB 256
#define TT 1024
#define II 128
#define HH 64

typedef float    f32x4_t __attribute__((ext_vector_type(4)));
typedef _Float16 h16x2   __attribute__((ext_vector_type(2)));
typedef _Float16 h16x4   __attribute__((ext_vector_type(4)));
typedef _Float16 h16x8   __attribute__((ext_vector_type(8)));
typedef __fp16   p16x2   __attribute__((ext_vector_type(2)));

union UH2 { unsigned u; h16x2 h; p16x2 p; };
union U4H8 { uint4 u; h16x8 h; };

__device__ __forceinline__ float tanh_fast(float x){
  // tanh(x) = 1 - 2/(1+e^{2x});  e^{2x} = exp2(x * 2/ln2)
  float e = __builtin_amdgcn_exp2f(x * 2.88539004f);
  return __builtin_fmaf(-2.0f, __builtin_amdgcn_rcpf(1.0f + e), 1.0f);
}

#if __has_builtin(__builtin_amdgcn_fdot2)
__device__ __forceinline__ float fdot2f(h16x2 a, h16x2 b, float c){
  return __builtin_amdgcn_fdot2(a, b, c, false);
}
#else
__device__ __forceinline__ float fdot2f(h16x2 a, h16x2 b, float c){
  return __builtin_fmaf((float)a[1], (float)b[1], __builtin_fmaf((float)a[0], (float)b[0], c));
}
#endif

// ---------------------------------------------------------------------------
// Workspace layout:
//   wsf (f32)  @ 0      [4160]: W_comm 64x64 row-major + combined bias[64]
//   whf (u32)  @ 16640  [2048]: W_comm rows as packed f16x2 pairs:
//                               whf[i*32+jp] = {f16(W[i][2jp]), f16(W[i][2jp+1])}
//   wsb (u16)  @ 24832  [8192]: W_in f16 MFMA B-fragments, frag-ready
// ---------------------------------------------------------------------------
__global__ void k_prep(const float* __restrict__ Ap, const float* __restrict__ Am,
                       const float* __restrict__ Winw,
                       const float* __restrict__ Winb, const float* __restrict__ bias,
                       float* __restrict__ wsf, unsigned* __restrict__ whf,
                       unsigned short* __restrict__ wsb){
  const int tid = threadIdx.x;
  for (int e = tid; e < 4096; e += 256){
    int i = e >> 6, j = e & 63;
    int is = i ^ 32, js = j ^ 32;
    float wp = Ap[i*64+j] + Ap[i*64+js] + Ap[is*64+j] + Ap[is*64+js];
    float wm = Am[i*64+j] - Am[i*64+js] - Am[is*64+j] + Am[is*64+js];
    wsf[e] = 0.25f * (wp + wm);
  }
  if (tid < 64) wsf[4096 + tid] = Winb[tid] + bias[tid];
  for (int e = tid; e < 8192; e += 256){
    int j = e & 7, lane = (e >> 3) & 63, fidx = e >> 9;
    int ks = fidx >> 2, nt = fidx & 3, l15 = lane & 15, q = lane >> 4;
    union { _Float16 f; unsigned short s; } cv;
    cv.f = (_Float16)Winw[(nt*16 + l15)*II + ks*32 + q*8 + j];
    wsb[e] = cv.s;
  }
  __syncthreads();
  for (int e = tid; e < 2048; e += 256){
    int i = e >> 5, jp = e & 31;
    UH2 p;
    p.h[0] = (_Float16)wsf[i*64 + 2*jp];
    p.h[1] = (_Float16)wsf[i*64 + 2*jp + 1];
    whf[e] = p.u;
  }
}

// ---------------------------------------------------------------------------
// Fused kernel: one block per batch (256 blocks x 256 thr), 128 KB dynamic LDS.
//   Phase 1 (all 4 waves): U[t][h] = f16(x[b,t,:] . W_in[h,:] + bc[h]) -> LDS.
//     f16 MFMA 16x16x32, wave w owns t-rows [w*256, w*256+256).
//     LDS layout: entry (tg, laneU) = 4 f16 u-values for t=tg*4+r, h=laneU
//     at byte offset (tg*64 + laneU)*8 -- exactly the recurrence's read shape.
//     MFMA C layout (col=l15 -> h, row=q*4+r -> 4 consecutive t) packs into
//     one uint2 per nt -> single ds_write_b64.
//   Phase 2 (wave 0; others exit): 1024-step recurrence, round-5 core:
//     lane i holds W_comm row i as 32 packed f16x2; per step DPP-neighbor
//     pack of h, 32 v_readlane + 32 v_dot2_f32_f16, fast tanh. u via
//     ds_read_b64 per 4 steps, prefetched 2 groups ahead.
//   128 KB LDS => exactly 1 block/CU; 256 blocks on 256 CUs.
// ---------------------------------------------------------------------------
__global__ __launch_bounds__(256, 1) void k_fused(const float* __restrict__ x,
                                                  const float* __restrict__ wsf,
                                                  const unsigned* __restrict__ whf,
                                                  const unsigned short* __restrict__ wsb,
                                                  const float* __restrict__ Wout,
                                                  const float* __restrict__ Woutb,
                                                  float* __restrict__ out){
  extern __shared__ unsigned char smem[];
  unsigned short* Us = (unsigned short*)smem;   // (tg*64 + laneU)*4 ushorts

  const int b    = blockIdx.x;
  const int tid  = threadIdx.x;
  const int lane = tid & 63;
  const int wave = tid >> 6;
  const int l15  = lane & 15;
  const int q    = lane >> 4;

  // ---------------- Phase 1: input projection into LDS ----------------
  {
    h16x8 bfr[4][4]; // [ks][nt]
    #pragma unroll
    for (int ks = 0; ks < 4; ++ks)
      #pragma unroll
      for (int nt = 0; nt < 4; ++nt)
        bfr[ks][nt] = *(const h16x8*)(wsb + ((ks*4 + nt)*64 + lane)*8);

    float bcv[4];
    #pragma unroll
    for (int nt = 0; nt < 4; ++nt) bcv[nt] = wsf[4096 + nt*16 + l15];

    const float* xb = x + (long)b * (TT * II);

    #pragma unroll 1
    for (int mt = 0; mt < 16; ++mt){
      const int trow = wave*256 + mt*16;
      const float* xa = xb + (trow + l15) * II + q*8;
      h16x8 afr[4];
      #pragma unroll
      for (int ks = 0; ks < 4; ++ks){
        float4 a0 = *(const float4*)(xa + ks*32);
        float4 a1 = *(const float4*)(xa + ks*32 + 4);
        U4H8 v;
        UH2 p0, p1, p2, p3;
        p0.p = __builtin_amdgcn_cvt_pkrtz(a0.x, a0.y);
        p1.p = __builtin_amdgcn_cvt_pkrtz(a0.z, a0.w);
        p2.p = __builtin_amdgcn_cvt_pkrtz(a1.x, a1.y);
        p3.p = __builtin_amdgcn_cvt_pkrtz(a1.z, a1.w);
        v.u.x = p0.u; v.u.y = p1.u; v.u.z = p2.u; v.u.w = p3.u;
        afr[ks] = v.h;
      }
      f32x4_t acc[4];
      #pragma unroll
      for (int nt = 0; nt < 4; ++nt){
        acc[nt][0]=bcv[nt]; acc[nt][1]=bcv[nt]; acc[nt][2]=bcv[nt]; acc[nt][3]=bcv[nt];
      }
      #pragma unroll
      for (int ks = 0; ks < 4; ++ks){
        #pragma unroll
        for (int nt = 0; nt < 4; ++nt){
          acc[nt] = __builtin_amdgcn_mfma_f32_16x16x32_f16(afr[ks], bfr[ks][nt], acc[nt], 0, 0, 0);
        }
      }
      // acc[nt][r]: h = nt*16 + l15, t = trow + q*4 + r  -> tg = trow/4 + q
      const int tg = (trow >> 2) + q;
      #pragma unroll
      for (int nt = 0; nt < 4; ++nt){
        UH2 lo, hi;
        lo.p = __builtin_amdgcn_cvt_pkrtz(acc[nt][0], acc[nt][1]);
        hi.p = __builtin_amdgcn_cvt_pkrtz(acc[nt][2], acc[nt][3]);
        uint2 pk; pk.x = lo.u; pk.y = hi.u;
        *(uint2*)&Us[(tg*64 + nt*16 + l15) * 4] = pk;
      }
    }
  }
  __syncthreads();
  if (wave != 0) return;

  // ---------------- Phase 2: recurrence (wave 0 only) ----------------
  h16x2 w[32];
  {
    const uint4* wr = (const uint4*)(whf + lane * 32);
    #pragma unroll
    for (int j4 = 0; j4 < 8; ++j4){
      uint4 v = wr[j4];
      UH2 c0, c1, c2, c3;
      c0.u = v.x; c1.u = v.y; c2.u = v.z; c3.u = v.w;
      w[4*j4+0] = c0.h; w[4*j4+1] = c1.h; w[4*j4+2] = c2.h; w[4*j4+3] = c3.h;
    }
  }

  const h16x4* Ul = (const h16x4*)Us;  // entry index = tg*64 + lane
  h16x4 uc = Ul[0*64 + lane];
  h16x4 u1 = Ul[1*64 + lane];

  float h = 0.0f;
  for (int tg = 0; tg < TT/4; ++tg){
    int tp = tg + 2; if (tp > TT/4 - 1) tp = TT/4 - 1;
    h16x4 u2 = Ul[tp*64 + lane];
    float ug0 = (float)uc[0], ug1 = (float)uc[1], ug2 = (float)uc[2], ug3 = (float)uc[3];
    #pragma unroll
    for (int g = 0; g < 4; ++g){
      float ugv = (g==0) ? ug0 : (g==1) ? ug1 : (g==2) ? ug2 : ug3;
      // neighbor h via DPP quad-perm [1,0,3,2] (VALU pipe)
      unsigned nbu = (unsigned)__builtin_amdgcn_mov_dpp(__float_as_uint(h), 0xB1, 0xF, 0xF, true);
      UH2 hp; hp.p = __builtin_amdgcn_cvt_pkrtz(h, __uint_as_float(nbu)); // valid on even lanes
      const unsigned hpu = hp.u;
      float a0 = ugv, a1 = 0.0f, a2 = 0.0f, a3 = 0.0f;
      #pragma unroll
      for (int jp = 0; jp < 32; jp += 4){
        UH2 b0, b1, b2, b3;
        b0.u = (unsigned)__builtin_amdgcn_readlane(hpu, 2*jp + 0);
        b1.u = (unsigned)__builtin_amdgcn_readlane(hpu, 2*jp + 2);
        b2.u = (unsigned)__builtin_amdgcn_readlane(hpu, 2*jp + 4);
        b3.u = (unsigned)__builtin_amdgcn_readlane(hpu, 2*jp + 6);
        a0 = fdot2f(w[jp+0], b0.h, a0);
        a1 = fdot2f(w[jp+1], b1.h, a1);
        a2 = fdot2f(w[jp+2], b2.h, a2);
        a3 = fdot2f(w[jp+3], b3.h, a3);
      }
      h = tanh_fast((a0 + a1) + (a2 + a3));
    }
    uc = u1; u1 = u2;
  }

  // Epilogue: predictions[b] = W_out @ h + W_out_b ; hidden[b] = h
  unsigned hu = __float_as_uint(h);
  float p0 = Woutb[lane];
  float p1 = Woutb[lane + 64];
  #pragma unroll 8
  for (int j = 0; j < 64; ++j){
    float hj = __uint_as_float(__builtin_amdgcn_readlane(hu, j));
    p0 = __builtin_fmaf(Wout[lane * HH + j],        hj, p0);
    p1 = __builtin_fmaf(Wout[(lane + 64) * HH + j], hj, p1);
  }
  out[b * 128 + lane]           = p0;
  out[b * 128 + 64 + lane]      = p1;
  out[BB * 128 + b * 64 + lane] = h;
}

// ---------------------------------------------------------------------------
extern "C" void kernel_launch(void* const* d_in, const int* in_sizes, int n_in,
                              void* d_out, int out_size, void* d_ws, size_t ws_size,
                              hipStream_t stream){
  const float* x     = (const float*)d_in[0];
  const float* Ap    = (const float*)d_in[1];
  const float* Am    = (const float*)d_in[2];
  const float* Winw  = (const float*)d_in[3];
  const float* Winb  = (const float*)d_in[4];
  const float* Woutw = (const float*)d_in[5];
  const float* Woutb = (const float*)d_in[6];
  const float* bias  = (const float*)d_in[7];

  float*          wsf = (float*)d_ws;
  unsigned*       whf = (unsigned*)((char*)d_ws + 16640);
  unsigned short* wsb = (unsigned short*)((char*)d_ws + 24832);

  float* out = (float*)d_out;

  static bool attr_set = false;
  hipFuncSetAttribute((const void*)k_fused,
                      hipFuncAttributeMaxDynamicSharedMemorySize, 131072);
  (void)attr_set;

  hipLaunchKernelGGL(k_prep,  dim3(1),   dim3(256), 0,      stream, Ap, Am, Winw, Winb, bias, wsf, whf, wsb);
  hipLaunchKernelGGL(k_fused, dim3(BB),  dim3(256), 131072, stream, x, wsf, whf, wsb, Woutw, Woutb, out);
}

// Round 7
// 333.009 us; speedup vs baseline: 2.3911x; 1.1475x over previous
//
#include <hip/hip_runtime.h>
#include <hip/hip_bf16.h>

// Problem constants
#define BB 256
#define TT 1024
#define II 128
#define HH 64

typedef float    f32x4_t __attribute__((ext_vector_type(4)));
typedef _Float16 h16x2   __attribute__((ext_vector_type(2)));
typedef _Float16 h16x4   __attribute__((ext_vector_type(4)));
typedef _Float16 h16x8   __attribute__((ext_vector_type(8)));
typedef __fp16   p16x2   __attribute__((ext_vector_type(2)));

union UH2 { unsigned u; h16x2 h; p16x2 p; };
union U4H8 { uint4 u; h16x8 h; };

__device__ __forceinline__ float tanh_fast(float x){
  // tanh(x) = 1 - 2/(1+e^{2x});  e^{2x} = exp2(x * 2/ln2)
  float e = __builtin_amdgcn_exp2f(x * 2.88539004f);
  return __builtin_fmaf(-2.0f, __builtin_amdgcn_rcpf(1.0f + e), 1.0f);
}

#if __has_builtin(__builtin_amdgcn_fdot2)
__device__ __forceinline__ float fdot2f(h16x2 a, h16x2 b, float c){
  return __builtin_amdgcn_fdot2(a, b, c, false);
}
#else
__device__ __forceinline__ float fdot2f(h16x2 a, h16x2 b, float c){
  return __builtin_fmaf((float)a[1], (float)b[1], __builtin_fmaf((float)a[0], (float)b[0], c));
}
#endif

// ---------------------------------------------------------------------------
// Workspace layout:
//   wsf (f32)  @ 0      [4160]: W_comm 64x64 row-major + combined bias[64]
//   whf (u32)  @ 16640  [2048]: W_comm rows as packed f16x2 pairs
//   wsb (u16)  @ 24832  [8192]: W_in f16 MFMA B-fragments, frag-ready
// ---------------------------------------------------------------------------
__global__ void k_prep(const float* __restrict__ Ap, const float* __restrict__ Am,
                       const float* __restrict__ Winw,
                       const float* __restrict__ Winb, const float* __restrict__ bias,
                       float* __restrict__ wsf, unsigned* __restrict__ whf,
                       unsigned short* __restrict__ wsb){
  const int tid = threadIdx.x;
  for (int e = tid; e < 4096; e += 256){
    int i = e >> 6, j = e & 63;
    int is = i ^ 32, js = j ^ 32;
    float wp = Ap[i*64+j] + Ap[i*64+js] + Ap[is*64+j] + Ap[is*64+js];
    float wm = Am[i*64+j] - Am[i*64+js] - Am[is*64+j] + Am[is*64+js];
    wsf[e] = 0.25f * (wp + wm);
  }
  if (tid < 64) wsf[4096 + tid] = Winb[tid] + bias[tid];
  for (int e = tid; e < 8192; e += 256){
    int j = e & 7, lane = (e >> 3) & 63, fidx = e >> 9;
    int ks = fidx >> 2, nt = fidx & 3, l15 = lane & 15, q = lane >> 4;
    union { _Float16 f; unsigned short s; } cv;
    cv.f = (_Float16)Winw[(nt*16 + l15)*II + ks*32 + q*8 + j];
    wsb[e] = cv.s;
  }
  __syncthreads();
  for (int e = tid; e < 2048; e += 256){
    int i = e >> 5, jp = e & 31;
    UH2 p;
    p.h[0] = (_Float16)wsf[i*64 + 2*jp];
    p.h[1] = (_Float16)wsf[i*64 + 2*jp + 1];
    whf[e] = p.u;
  }
}

// ---------------------------------------------------------------------------
// Fused producer/consumer kernel: one block per batch (256 blocks x 256 thr),
// 128 KB + 256 B dynamic LDS. Waves sit on 4 different SIMDs -> producer work
// costs the consumer zero issue slots.
//   Producers (waves 1..3): 64 t-tiles (16 rows) round-robin (tile % 3).
//     Tile: f16 MFMA 16x16x32 projection of x rows -> LDS in recurrence-ready
//     layout (entry (tg,h) at (tg*64+h)*8 bytes = 4 consecutive t as f16x4).
//     Publish: __threadfence_block (wave-level lgkmcnt drain) + release flag.
//   Consumer (wave 0): starts immediately; polls flags[tile+1] once per tile
//     (16 steps) which also covers the 2-group read-ahead; runs the round-5
//     recurrence core (32 readlane + 32 fdot2 per step) and the epilogue.
// ---------------------------------------------------------------------------
__global__ __launch_bounds__(256, 1) void k_fused(const float* __restrict__ x,
                                                  const float* __restrict__ wsf,
                                                  const unsigned* __restrict__ whf,
                                                  const unsigned short* __restrict__ wsb,
                                                  const float* __restrict__ Wout,
                                                  const float* __restrict__ Woutb,
                                                  float* __restrict__ out){
  extern __shared__ unsigned char smem[];
  unsigned short* Us    = (unsigned short*)smem;          // 128 KB U buffer
  unsigned*       flags = (unsigned*)(smem + 131072);     // 64 tile flags

  const int b    = blockIdx.x;
  const int tid  = threadIdx.x;
  const int lane = tid & 63;
  const int wave = tid >> 6;
  const int l15  = lane & 15;
  const int q    = lane >> 4;

  if (tid < 64) flags[tid] = 0u;
  __syncthreads();

  if (wave != 0){
    // ---------------- Producers: waves 1..3 ----------------
    h16x8 bfr[4][4]; // [ks][nt]
    #pragma unroll
    for (int ks = 0; ks < 4; ++ks)
      #pragma unroll
      for (int nt = 0; nt < 4; ++nt)
        bfr[ks][nt] = *(const h16x8*)(wsb + ((ks*4 + nt)*64 + lane)*8);

    float bcv[4];
    #pragma unroll
    for (int nt = 0; nt < 4; ++nt) bcv[nt] = wsf[4096 + nt*16 + l15];

    const float* xb = x + (long)b * (TT * II);

    #pragma unroll 1
    for (int tile = wave - 1; tile < 64; tile += 3){
      const int trow = tile * 16;
      const float* xa = xb + (trow + l15) * II + q*8;
      h16x8 afr[4];
      #pragma unroll
      for (int ks = 0; ks < 4; ++ks){
        float4 a0 = *(const float4*)(xa + ks*32);
        float4 a1 = *(const float4*)(xa + ks*32 + 4);
        U4H8 v;
        UH2 p0, p1, p2, p3;
        p0.p = __builtin_amdgcn_cvt_pkrtz(a0.x, a0.y);
        p1.p = __builtin_amdgcn_cvt_pkrtz(a0.z, a0.w);
        p2.p = __builtin_amdgcn_cvt_pkrtz(a1.x, a1.y);
        p3.p = __builtin_amdgcn_cvt_pkrtz(a1.z, a1.w);
        v.u.x = p0.u; v.u.y = p1.u; v.u.z = p2.u; v.u.w = p3.u;
        afr[ks] = v.h;
      }
      f32x4_t acc[4];
      #pragma unroll
      for (int nt = 0; nt < 4; ++nt){
        acc[nt][0]=bcv[nt]; acc[nt][1]=bcv[nt]; acc[nt][2]=bcv[nt]; acc[nt][3]=bcv[nt];
      }
      #pragma unroll
      for (int ks = 0; ks < 4; ++ks){
        #pragma unroll
        for (int nt = 0; nt < 4; ++nt){
          acc[nt] = __builtin_amdgcn_mfma_f32_16x16x32_f16(afr[ks], bfr[ks][nt], acc[nt], 0, 0, 0);
        }
      }
      // acc[nt][r]: h = nt*16 + l15, t = trow + q*4 + r  -> tg = tile*4 + q
      const int tg = tile*4 + q;
      #pragma unroll
      for (int nt = 0; nt < 4; ++nt){
        UH2 lo, hi;
        lo.p = __builtin_amdgcn_cvt_pkrtz(acc[nt][0], acc[nt][1]);
        hi.p = __builtin_amdgcn_cvt_pkrtz(acc[nt][2], acc[nt][3]);
        uint2 pk; pk.x = lo.u; pk.y = hi.u;
        *(uint2*)&Us[(tg*64 + nt*16 + l15) * 4] = pk;
      }
      __threadfence_block();  // wave-level lgkmcnt drain: all lanes' ds_writes done
      if (lane == 0)
        __hip_atomic_store(&flags[tile], 1u, __ATOMIC_RELEASE, __HIP_MEMORY_SCOPE_WORKGROUP);
    }
    return;
  }

  // ---------------- Consumer: wave 0 ----------------
  h16x2 w[32];
  {
    const uint4* wr = (const uint4*)(whf + lane * 32);
    #pragma unroll
    for (int j4 = 0; j4 < 8; ++j4){
      uint4 v = wr[j4];
      UH2 c0, c1, c2, c3;
      c0.u = v.x; c1.u = v.y; c2.u = v.z; c3.u = v.w;
      w[4*j4+0] = c0.h; w[4*j4+1] = c1.h; w[4*j4+2] = c2.h; w[4*j4+3] = c3.h;
    }
  }

  // Wait for tile 0 before the initial u loads.
  while (!__hip_atomic_load(&flags[0], __ATOMIC_ACQUIRE, __HIP_MEMORY_SCOPE_WORKGROUP)) {}

  const h16x4* Ul = (const h16x4*)Us;  // entry index = tg*64 + lane
  h16x4 uc = Ul[0*64 + lane];
  h16x4 u1 = Ul[1*64 + lane];

  float h = 0.0f;
  int last_ready = 0;
  #pragma unroll 1
  for (int tile = 0; tile < 64; ++tile){
    int wt = tile + 1; if (wt > 63) wt = 63;
    if (wt > last_ready){
      while (!__hip_atomic_load(&flags[wt], __ATOMIC_ACQUIRE, __HIP_MEMORY_SCOPE_WORKGROUP)) {}
      last_ready = wt;
    }
    #pragma unroll
    for (int tgl = 0; tgl < 4; ++tgl){
      const int tg = tile*4 + tgl;
      int tp = tg + 2; if (tp > TT/4 - 1) tp = TT/4 - 1;
      h16x4 u2 = Ul[tp*64 + lane];
      float ug0 = (float)uc[0], ug1 = (float)uc[1], ug2 = (float)uc[2], ug3 = (float)uc[3];
      #pragma unroll
      for (int g = 0; g < 4; ++g){
        float ugv = (g==0) ? ug0 : (g==1) ? ug1 : (g==2) ? ug2 : ug3;
        // neighbor h via DPP quad-perm [1,0,3,2] (VALU pipe)
        unsigned nbu = (unsigned)__builtin_amdgcn_mov_dpp(__float_as_uint(h), 0xB1, 0xF, 0xF, true);
        UH2 hp; hp.p = __builtin_amdgcn_cvt_pkrtz(h, __uint_as_float(nbu)); // valid on even lanes
        const unsigned hpu = hp.u;
        float a0 = ugv, a1 = 0.0f, a2 = 0.0f, a3 = 0.0f;
        #pragma unroll
        for (int jp = 0; jp < 32; jp += 4){
          UH2 b0, b1, b2, b3;
          b0.u = (unsigned)__builtin_amdgcn_readlane(hpu, 2*jp + 0);
          b1.u = (unsigned)__builtin_amdgcn_readlane(hpu, 2*jp + 2);
          b2.u = (unsigned)__builtin_amdgcn_readlane(hpu, 2*jp + 4);
          b3.u = (unsigned)__builtin_amdgcn_readlane(hpu, 2*jp + 6);
          a0 = fdot2f(w[jp+0], b0.h, a0);
          a1 = fdot2f(w[jp+1], b1.h, a1);
          a2 = fdot2f(w[jp+2], b2.h, a2);
          a3 = fdot2f(w[jp+3], b3.h, a3);
        }
        h = tanh_fast((a0 + a1) + (a2 + a3));
      }
      uc = u1; u1 = u2;
    }
  }

  // Epilogue: predictions[b] = W_out @ h + W_out_b ; hidden[b] = h
  unsigned hu = __float_as_uint(h);
  float p0 = Woutb[lane];
  float p1 = Woutb[lane + 64];
  #pragma unroll 8
  for (int j = 0; j < 64; ++j){
    float hj = __uint_as_float(__builtin_amdgcn_readlane(hu, j));
    p0 = __builtin_fmaf(Wout[lane * HH + j],        hj, p0);
    p1 = __builtin_fmaf(Wout[(lane + 64) * HH + j], hj, p1);
  }
  out[b * 128 + lane]           = p0;
  out[b * 128 + 64 + lane]      = p1;
  out[BB * 128 + b * 64 + lane] = h;
}

// ---------------------------------------------------------------------------
extern "C" void kernel_launch(void* const* d_in, const int* in_sizes, int n_in,
                              void* d_out, int out_size, void* d_ws, size_t ws_size,
                              hipStream_t stream){
  const float* x     = (const float*)d_in[0];
  const float* Ap    = (const float*)d_in[1];
  const float* Am    = (const float*)d_in[2];
  const float* Winw  = (const float*)d_in[3];
  const float* Winb  = (const float*)d_in[4];
  const float* Woutw = (const float*)d_in[5];
  const float* Woutb = (const float*)d_in[6];
  const float* bias  = (const float*)d_in[7];

  float*          wsf = (float*)d_ws;
  unsigned*       whf = (unsigned*)((char*)d_ws + 16640);
  unsigned short* wsb = (unsigned short*)((char*)d_ws + 24832);

  float* out = (float*)d_out;

  hipFuncSetAttribute((const void*)k_fused,
                      hipFuncAttributeMaxDynamicSharedMemorySize, 131328);

  hipLaunchKernelGGL(k_prep,  dim3(1),   dim3(256), 0,      stream, Ap, Am, Winw, Winb, bias, wsf, whf, wsb);
  hipLaunchKernelGGL(k_fused, dim3(BB),  dim3(256), 131328, stream, x, wsf, whf, wsb, Woutw, Woutb, out);
}